// Round 4
// baseline (359.271 us; speedup 1.0000x reference)
//
#include <hip/hip_runtime.h>

// Problem constants
#define T_DIM   100
#define N_NODES 25
#define C_DIM   128
#define GNV     3200          // N_NODES * C_DIM (per-graph elements)
#define CNT_PER_T 204800.0f   // B * N * C
#define GRID_MAIN 800         // co-resident: LDS 38.4KB -> 4 blk/CU -> 1024 max

// ws float offsets
#define WS_A2P  0             // 1024 bf16 (512 floats): A2 bf16, zero-padded 32x32 [m][k]
#define WS_RS1  640           // 25 floats: rowsum(Ahat)
#define WS_BW   768           // 128 floats: W2^T b1
#define WS_W12T 2048          // 16384 bf16 (= 8192 floats): W12^T, [c][v]
#define WS_PART 10240         // 3200 floats: per-(t,bq) partial sums [0,1600) / ssqs [1600,3200)
#define WS_CNT  13440         // 100 uints: per-t arrival counters

// Y_T layout in LDS: [g][c][row], row-stride 36 shorts (72 B: 18-dword stride,
// gcd(18,32)=2 -> 16-bank spread, 2-way free; 8B-aligned for b64 access).
#define YSTR  36
#define YGSTR (128 * YSTR)    // 4608 shorts per graph

typedef __attribute__((ext_vector_type(8))) short short8;
typedef __attribute__((ext_vector_type(4))) float f32x4;

__device__ __forceinline__ unsigned short f2bf(float f) {
  unsigned int u = __float_as_uint(f);
  u += 0x7FFFu + ((u >> 16) & 1u);   // RNE
  return (unsigned short)(u >> 16);
}
__device__ __forceinline__ unsigned int pack2bf(float a, float b) {
  return (unsigned int)f2bf(a) | ((unsigned int)f2bf(b) << 16);
}

// ---------------------------------------------------------------------------
// k_pre: blocks 0..63 = W12T/bw prep; block 64 = adjacency prep + cnt reset.
// Separate kernel launch => prep data visibility via kernel boundary (proven).
__global__ void k_pre(const int* __restrict__ edge, const float* __restrict__ W1,
                      const float* __restrict__ W2, const float* __restrict__ b1,
                      float* __restrict__ wsf) {
  __shared__ float sA[N_NODES * N_NODES];
  __shared__ float sA2[N_NODES * N_NODES];
  __shared__ float sdeg[N_NODES];
  __shared__ float sdis[N_NODES];
  const int tid = threadIdx.x;  // 256

  if (blockIdx.x < 64) {
    // W12T[c][v] = sum_u W1[v][u]*W2[u][c]  (bf16), bw = W2^T b1.
    int j = blockIdx.x * 256 + tid;          // 16384
    int c = j & 127, v = j >> 7;             // v wave-uniform
    float acc = 0.f;
#pragma unroll 8
    for (int u = 0; u < 128; u++) acc = fmaf(W1[v * 128 + u], W2[u * 128 + c], acc);
    ((unsigned short*)(wsf + WS_W12T))[c * 128 + v] = f2bf(acc);
    if (j < 128) {
      float a2 = 0.f;
      for (int u = 0; u < 128; u++) a2 = fmaf(W2[u * 128 + j], b1[u], a2);
      wsf[WS_BW + j] = a2;
    }
    return;
  }

  // ---- block 64: normalized adjacency, A2 = Ahat^2 (bf16 padded), rowsums.
  if (tid < N_NODES) sdeg[tid] = 0.f;
  for (int j = tid; j < N_NODES * N_NODES; j += 256) sA[j] = 0.f;
  __syncthreads();
  if (tid < 64) atomicAdd(&sdeg[edge[64 + tid]], 1.f);  // tgt occurrences
  __syncthreads();
  if (tid < N_NODES) sdis[tid] = rsqrtf(sdeg[tid] + 1.f);  // +1 self-loop
  __syncthreads();
  if (tid < 64) {
    int s = edge[tid], tg = edge[64 + tid];
    atomicAdd(&sA[tg * N_NODES + s], sdis[s] * sdis[tg]);
  }
  __syncthreads();
  if (tid < N_NODES) atomicAdd(&sA[tid * N_NODES + tid], sdis[tid] * sdis[tid]);
  __syncthreads();
  for (int j = tid; j < N_NODES * N_NODES; j += 256) {
    int n = j / N_NODES, m = j - n * N_NODES;
    float acc = 0.f;
    for (int k = 0; k < N_NODES; k++) acc = fmaf(sA[n * N_NODES + k], sA[k * N_NODES + m], acc);
    sA2[j] = acc;
  }
  __syncthreads();
  // A2 bf16, zero-padded to 32x32 row-major [m][k]
  for (int j = tid; j < 1024; j += 256) {
    int m = j >> 5, k = j & 31;
    float v = (m < N_NODES && k < N_NODES) ? sA2[m * N_NODES + k] : 0.f;
    ((unsigned short*)(wsf + WS_A2P))[j] = f2bf(v);
  }
  if (tid < N_NODES) {
    float rs = 0.f;
    for (int m = 0; m < N_NODES; m++) rs += sA[tid * N_NODES + m];
    wsf[WS_RS1 + tid] = rs;
  }
  // reset per-t arrival counters (agent-scope atomic store, coherence point)
  if (tid < T_DIM)
    __hip_atomic_store((unsigned int*)(wsf + WS_CNT) + tid, 0u,
                       __ATOMIC_RELEASE, __HIP_MEMORY_SCOPE_AGENT);
}

// ---------------------------------------------------------------------------
// k_mainnorm: per block 2 chunks x 4 graphs (verified MFMA pipeline), then
// per-t spin (cnt==16) and BatchNorm+affine+ReLU over the block's OWN 8
// graphs. All cross-block data goes through agent-scope atomics; no
// grid-wide barrier, no cooperative launch. 800 blocks all co-resident.
__global__ __launch_bounds__(256, 4) void k_mainnorm(
    const float* __restrict__ x, const float* __restrict__ b2,
    const float* __restrict__ gamma, const float* __restrict__ beta,
    float* __restrict__ wsf, float* __restrict__ out) {
  __shared__ __align__(16) unsigned short LB[4 * YGSTR];  // 36864 B union:
  //   phase A: X view, [row 0..111][k 0..127], XOR-swizzled, rows 28/graph
  //   phase B: Y_T view, [g][c][row] stride YSTR
  __shared__ float sBW[128];
  __shared__ float sB2[128];
  __shared__ float rs1[32];
  __shared__ float red[8];
  __shared__ float sred[2];
  const int tid = threadIdx.x;
  const int bid = blockIdx.x;
  const int wv = tid >> 6, lane = tid & 63, quad = lane >> 4, l16 = lane & 15;

  if (tid < 128) {
    sBW[tid] = wsf[WS_BW + tid];
    if (tid < N_NODES) rs1[tid] = wsf[WS_RS1 + tid];
  } else {
    sB2[tid - 128] = b2[tid - 128];
  }

  // W12T B-fragments straight from global (L2-hot), into regs. Chunk-invariant.
  short8 bfr[2][4];
  {
    const unsigned short* Wg = (const unsigned short*)(wsf + WS_W12T);
#pragma unroll
    for (int nt = 0; nt < 2; nt++) {
      const short8* rp = (const short8*)&Wg[(wv * 32 + nt * 16 + l16) * 128];
#pragma unroll
      for (int ks = 0; ks < 4; ks++) bfr[nt][ks] = rp[(ks << 2) | quad];
    }
  }
  // A2 fragments (stage 2), chunk-invariant.
  const unsigned short* A2p = (const unsigned short*)(wsf + WS_A2P);
  short8 a2f[2];
#pragma unroll
  for (int mt2 = 0; mt2 < 2; mt2++)
    a2f[mt2] = *(const short8*)&A2p[(mt2 * 16 + l16) * 32 + quad * 8];

  for (int iter = 0; iter < 2; iter++) {
    const int chunk = bid + iter * GRID_MAIN;
    const int t = chunk % T_DIM;
    const int bq = chunk / T_DIM;            // unique partial slot per (t,bq)
    __syncthreads();  // prior-chunk LB reads (or sBW stores) complete

    // zero X pad rows (3 per graph: g*28+25..27)
    for (int j = tid; j < 12 * 128; j += 256) {
      int pr = j >> 7;                       // 0..11
      int g = pr / 3, rr = pr - (pr / 3) * 3;
      LB[(g * 28 + 25 + rr) * 128 + (j & 127)] = 0;
    }

    // Load X (fp32) vectorized: 1600 chunks of 8 consecutive v (32B), bf16
    // convert, one swizzled 16B LDS write each. XOR-swizzle flips only bits
    // >=3 of v, so 8-aligned chunks stay contiguous 16B blocks.
    {
      const float* xb = x + (bq * 4 * T_DIM + t) * GNV;
      for (int idx = tid; idx < 1600; idx += 256) {
        int row = idx >> 4;                  // 0..99  (4 graphs x 25 rows)
        int c8  = (idx & 15) << 3;           // v0 = 0..120 step 8
        int g = (row * 41) >> 10;            // row / 25 (exact for row<100)
        int n = row - g * 25;
        const float4* xp = (const float4*)(xb + g * (T_DIM * GNV) + n * 128 + c8);
        float4 f0 = xp[0], f1 = xp[1];
        uint4 w;
        w.x = pack2bf(f0.x, f0.y); w.y = pack2bf(f0.z, f0.w);
        w.z = pack2bf(f1.x, f1.y); w.w = pack2bf(f1.z, f1.w);
        int r = g * 28 + n;
        *(uint4*)&LB[r * 128 + (c8 ^ ((r & 15) << 3))] = w;
      }
    }
    __syncthreads();

    // ---- Stage 1: Y = X * W12. Wave wv covers c in [wv*32, +32). 56 MFMA.
    f32x4 acc[7][2];
#pragma unroll
    for (int mt = 0; mt < 7; mt++)
#pragma unroll
      for (int nt = 0; nt < 2; nt++)
#pragma unroll
        for (int r = 0; r < 4; r++) acc[mt][nt][r] = 0.f;

#pragma unroll
    for (int ks = 0; ks < 4; ks++) {
      const int cc = (ks << 2) | quad;
#pragma unroll
      for (int mt = 0; mt < 7; mt++) {
        int arow = mt * 16 + l16;
        short8 afr = *(const short8*)&LB[arow * 128 + ((cc ^ (arow & 15)) << 3)];
#pragma unroll
        for (int nt = 0; nt < 2; nt++)
          acc[mt][nt] = __builtin_amdgcn_mfma_f32_16x16x32_bf16(afr, bfr[nt][ks], acc[mt][nt], 0, 0, 0);
      }
    }
    __syncthreads();  // all X reads done; LB becomes Y_T

    // Write Y -> Y_T (bf16). Each frag: 4 consecutive rows (one graph), col c.
#pragma unroll
    for (int mt = 0; mt < 7; mt++) {
      int row0 = mt * 16 + quad * 4;
      int g = row0 / 28;
      int rl = row0 - g * 28;              // multiple of 4 -> 8B aligned
#pragma unroll
      for (int nt = 0; nt < 2; nt++) {
        int c = wv * 32 + nt * 16 + l16;
        uint2 p;
        p.x = pack2bf(acc[mt][nt][0], acc[mt][nt][1]);
        p.y = pack2bf(acc[mt][nt][2], acc[mt][nt][3]);
        *(uint2*)&LB[g * YGSTR + c * YSTR + rl] = p;
      }
    }
    // zero Y_T pad rows 28..31
    {
      uint2 z; z.x = 0u; z.y = 0u;
      for (int j = tid; j < 512; j += 256) {
        int g = j >> 7, c = j & 127;
        *(uint2*)&LB[g * YGSTR + c * YSTR + 28] = z;
      }
    }
    __syncthreads();

    // ---- Stage 2: H_g = A2 * Y_g. Wave wv <-> graph wv. 16 MFMA.
    const int obase = ((bq * 4 + wv) * T_DIM + t) * GNV;
    float sum = 0.f, ssq = 0.f;
#pragma unroll
    for (int half = 0; half < 2; half++) {
      f32x4 acc2[2][4];
#pragma unroll
      for (int mt2 = 0; mt2 < 2; mt2++)
#pragma unroll
        for (int nt = 0; nt < 4; nt++)
#pragma unroll
          for (int r = 0; r < 4; r++) acc2[mt2][nt][r] = 0.f;

#pragma unroll
      for (int nt = 0; nt < 4; nt++) {
        int c = (half * 4 + nt) * 16 + l16;
        int base = wv * YGSTR + c * YSTR + quad * 8;
        uint2 lo = *(const uint2*)&LB[base];
        uint2 hi = *(const uint2*)&LB[base + 4];
        uint4 w; w.x = lo.x; w.y = lo.y; w.z = hi.x; w.w = hi.y;
        short8 bf = __builtin_bit_cast(short8, w);
#pragma unroll
        for (int mt2 = 0; mt2 < 2; mt2++)
          acc2[mt2][nt] = __builtin_amdgcn_mfma_f32_16x16x32_bf16(a2f[mt2], bf, acc2[mt2][nt], 0, 0, 0);
      }
      // Epilogue for this half: bias + store + stats.
#pragma unroll
      for (int mt2 = 0; mt2 < 2; mt2++) {
#pragma unroll
        for (int nt = 0; nt < 4; nt++) {
          int c = (half * 4 + nt) * 16 + l16;
          float bw = sBW[c], bb = sB2[c];
#pragma unroll
          for (int r = 0; r < 4; r++) {
            int m = mt2 * 16 + quad * 4 + r;
            if (m < N_NODES) {
              float v = acc2[mt2][nt][r] + rs1[m] * bw + bb;
              out[obase + m * 128 + c] = v;
              sum += v;
              ssq += v * v;
            }
          }
        }
      }
    }

#pragma unroll
    for (int off = 32; off > 0; off >>= 1) {
      sum += __shfl_down(sum, off, 64);
      ssq += __shfl_down(ssq, off, 64);
    }
    if (lane == 0) { red[wv] = sum; red[4 + wv] = ssq; }
    __syncthreads();
    if (tid == 0) {
      float bs = red[0] + red[1] + red[2] + red[3];
      float bsq = red[4] + red[5] + red[6] + red[7];
      float* part = wsf + WS_PART;
      __hip_atomic_store(&part[t * 16 + bq], bs,
                         __ATOMIC_RELAXED, __HIP_MEMORY_SCOPE_AGENT);
      __hip_atomic_store(&part[1600 + t * 16 + bq], bsq,
                         __ATOMIC_RELAXED, __HIP_MEMORY_SCOPE_AGENT);
      // release: both partial stores visible before the count ticks
      __hip_atomic_fetch_add((unsigned int*)(wsf + WS_CNT) + t, 1u,
                             __ATOMIC_RELEASE, __HIP_MEMORY_SCOPE_AGENT);
    }
  }

  // ======= Norm phase: wait for this t's 16 contributions, then RMW own 8 =======
  {
    const int tn = bid % T_DIM;          // same t for both chunks (800%100==0)
    if (tid == 0) {
      unsigned int* cnt = (unsigned int*)(wsf + WS_CNT) + tn;
      while (__hip_atomic_load(cnt, __ATOMIC_ACQUIRE, __HIP_MEMORY_SCOPE_AGENT) < 16u)
        __builtin_amdgcn_s_sleep(1);
    }
    __syncthreads();
    if (tid < 32) {
      const float* pp = wsf + WS_PART + (tid < 16 ? 0 : 1600) + tn * 16 + (tid & 15);
      float v = __hip_atomic_load(pp, __ATOMIC_RELAXED, __HIP_MEMORY_SCOPE_AGENT);
      v += __shfl_xor(v, 8, 64);
      v += __shfl_xor(v, 4, 64);
      v += __shfl_xor(v, 2, 64);
      v += __shfl_xor(v, 1, 64);
      if ((tid & 15) == 0) sred[tid >> 4] = v;
    }
    __syncthreads();
    const float inv = 1.f / CNT_PER_T;
    float mean = sred[0] * inv;
    float var = fmaf(sred[1], inv, -mean * mean);
    float rstd = rsqrtf(var + 1e-5f);
    float gm = gamma[tn] * rstd;
    float bt = fmaf(-mean, gm, beta[tn]);
#pragma unroll
    for (int it = 0; it < 2; it++) {
      int bq2 = (bid + it * GRID_MAIN) / T_DIM;
#pragma unroll
      for (int gl = 0; gl < 4; gl++) {
        float* p = out + ((bq2 * 4 + gl) * T_DIM + tn) * GNV;
        for (int j = tid; j < GNV / 4; j += 256) {
          float4 v = *(const float4*)(p + 4 * j);
          v.x = fmaxf(fmaf(v.x, gm, bt), 0.f);
          v.y = fmaxf(fmaf(v.y, gm, bt), 0.f);
          v.z = fmaxf(fmaf(v.z, gm, bt), 0.f);
          v.w = fmaxf(fmaf(v.w, gm, bt), 0.f);
          *(float4*)(p + 4 * j) = v;
        }
      }
    }
  }
}

// ---------------------------------------------------------------------------
extern "C" void kernel_launch(void* const* d_in, const int* in_sizes, int n_in,
                              void* d_out, int out_size, void* d_ws, size_t ws_size,
                              hipStream_t stream) {
  const float* x     = (const float*)d_in[0];
  const int*   edge  = (const int*)d_in[1];
  const float* W1    = (const float*)d_in[2];
  const float* b1    = (const float*)d_in[3];
  const float* W2    = (const float*)d_in[4];
  const float* b2    = (const float*)d_in[5];
  const float* gamma = (const float*)d_in[6];
  const float* beta  = (const float*)d_in[7];
  float* out = (float*)d_out;
  float* wsf = (float*)d_ws;

  k_pre<<<65, 256, 0, stream>>>(edge, W1, W2, b1, wsf);
  k_mainnorm<<<GRID_MAIN, 256, 0, stream>>>(x, b2, gamma, beta, wsf, out);
}

// Round 5
// 199.313 us; speedup vs baseline: 1.8025x; 1.8025x over previous
//
#include <hip/hip_runtime.h>

// Problem constants
#define T_DIM   100
#define N_NODES 25
#define C_DIM   128
#define G_TOTAL 6400          // B*T
#define GNV     3200          // N_NODES * C_DIM (per-graph elements)
#define TOT_ELEM 20480000     // G_TOTAL * GNV
#define CNT_PER_T 204800.0f   // B * N * C

// ws float offsets
#define WS_A2P  0             // 1024 bf16 (512 floats): A2 bf16, zero-padded 32x32 [m][k]
#define WS_RS1  640           // 25 floats: rowsum(Ahat)
#define WS_BW   768           // 128 floats: W2^T b1
#define WS_SUM  1024          // 100 floats: per-t sum   (zeroed each call)
#define WS_SSQ  1152          // 100 floats: per-t sumsq
#define WS_W12T 2048          // 16384 bf16 (= 8192 floats): W12^T, [c][v]
#define WS_HB   16384         // bf16 H buffer (TOT_ELEM ushorts = 40.96 MB), if ws fits

// Y_T layout in LDS: [g][c][row], row-stride 36 shorts (72 B: 18-dword stride,
// gcd(18,32)=2 -> 16-bank spread, 2-way free; 8B-aligned for b64 access).
#define YSTR  36
#define YGSTR (128 * YSTR)    // 4608 shorts per graph

typedef __attribute__((ext_vector_type(8))) short short8;
typedef __attribute__((ext_vector_type(4))) float f32x4;

__device__ __forceinline__ unsigned short f2bf(float f) {
  unsigned int u = __float_as_uint(f);
  u += 0x7FFFu + ((u >> 16) & 1u);   // RNE
  return (unsigned short)(u >> 16);
}
__device__ __forceinline__ float bf2f(unsigned short h) {
  return __uint_as_float(((unsigned int)h) << 16);
}
__device__ __forceinline__ unsigned int pack2bf(float a, float b) {
  return (unsigned int)f2bf(a) | ((unsigned int)f2bf(b) << 16);
}

// ---------------------------------------------------------------------------
// k_pre: blocks 0..63 = W12T/bw prep; block 64 = adjacency prep (independent).
__global__ void k_pre(const int* __restrict__ edge, const float* __restrict__ W1,
                      const float* __restrict__ W2, const float* __restrict__ b1,
                      float* __restrict__ wsf) {
  __shared__ float sA[N_NODES * N_NODES];
  __shared__ float sA2[N_NODES * N_NODES];
  __shared__ float sdeg[N_NODES];
  __shared__ float sdis[N_NODES];
  const int tid = threadIdx.x;  // 256

  if (blockIdx.x < 64) {
    // W12T[c][v] = sum_u W1[v][u]*W2[u][c]  (bf16), bw = W2^T b1.
    int j = blockIdx.x * 256 + tid;          // 16384
    int c = j & 127, v = j >> 7;             // v wave-uniform
    float acc = 0.f;
#pragma unroll 8
    for (int u = 0; u < 128; u++) acc = fmaf(W1[v * 128 + u], W2[u * 128 + c], acc);
    ((unsigned short*)(wsf + WS_W12T))[c * 128 + v] = f2bf(acc);
    if (j < 128) {
      float a2 = 0.f;
      for (int u = 0; u < 128; u++) a2 = fmaf(W2[u * 128 + j], b1[u], a2);
      wsf[WS_BW + j] = a2;
    }
    return;
  }

  // ---- block 64: normalized adjacency, A2 = Ahat^2 (bf16 padded), rowsums.
  if (tid < N_NODES) sdeg[tid] = 0.f;
  for (int j = tid; j < N_NODES * N_NODES; j += 256) sA[j] = 0.f;
  __syncthreads();
  if (tid < 64) atomicAdd(&sdeg[edge[64 + tid]], 1.f);  // tgt occurrences
  __syncthreads();
  if (tid < N_NODES) sdis[tid] = rsqrtf(sdeg[tid] + 1.f);  // +1 self-loop
  __syncthreads();
  if (tid < 64) {
    int s = edge[tid], tg = edge[64 + tid];
    atomicAdd(&sA[tg * N_NODES + s], sdis[s] * sdis[tg]);
  }
  __syncthreads();
  if (tid < N_NODES) atomicAdd(&sA[tid * N_NODES + tid], sdis[tid] * sdis[tid]);
  __syncthreads();
  for (int j = tid; j < N_NODES * N_NODES; j += 256) {
    int n = j / N_NODES, m = j - n * N_NODES;
    float acc = 0.f;
    for (int k = 0; k < N_NODES; k++) acc = fmaf(sA[n * N_NODES + k], sA[k * N_NODES + m], acc);
    sA2[j] = acc;
  }
  __syncthreads();
  // A2 bf16, zero-padded to 32x32 row-major [m][k]
  for (int j = tid; j < 1024; j += 256) {
    int m = j >> 5, k = j & 31;
    float v = (m < N_NODES && k < N_NODES) ? sA2[m * N_NODES + k] : 0.f;
    ((unsigned short*)(wsf + WS_A2P))[j] = f2bf(v);
  }
  if (tid < N_NODES) {
    float rs = 0.f;
    for (int m = 0; m < N_NODES; m++) rs += sA[tid * N_NODES + m];
    wsf[WS_RS1 + tid] = rs;
  }
  if (tid < T_DIM) { wsf[WS_SUM + tid] = 0.f; wsf[WS_SSQ + tid] = 0.f; }
}

// ---------------------------------------------------------------------------
// k_main core (shared by both variants via template): per block 4 graphs
// (same t, b = bq*4..+3), rows padded 28/graph.
//   Stage 1 (MFMA): Y = X_bf16 * W12            (X staged in LDS, swizzled)
//   Stage 2 (MFMA): H_g = A2_bf16 * Y_g         (Y_T in LDS, wave = graph)
//   Epilogue: H += rs1[n]*bw[c] + b2[c];
//     BF16H=1: store bf16 H to hb (half the write bytes), stats on rounded H.
//     BF16H=0: store fp32 H to outf (proven fallback).
template <int BF16H>
__device__ __forceinline__ void k_main_body(const float* __restrict__ x,
                                            const float* __restrict__ b2,
                                            const float* __restrict__ wsc,
                                            float* __restrict__ stats,
                                            unsigned short* __restrict__ hb,
                                            float* __restrict__ outf) {
  __shared__ __align__(16) unsigned short LB[4 * YGSTR];  // 36864 B union
  __shared__ float sBW[128];
  __shared__ float sB2[128];
  __shared__ float rs1[32];
  __shared__ float red[8];
  const int tid = threadIdx.x;
  const int bid = blockIdx.x;
  const int t = bid % T_DIM;
  const int bq = bid / T_DIM;
  const int wv = tid >> 6, lane = tid & 63, quad = lane >> 4, l16 = lane & 15;

  if (tid < 128) {
    sBW[tid] = wsc[WS_BW + tid];
    if (tid < N_NODES) rs1[tid] = wsc[WS_RS1 + tid];
  } else {
    sB2[tid - 128] = b2[tid - 128];
  }
  // zero X pad rows (3 per graph: g*28+25..27)
  for (int j = tid; j < 12 * 128; j += 256) {
    int pr = j >> 7;                       // 0..11
    int g = pr / 3, rr = pr - (pr / 3) * 3;
    LB[(g * 28 + 25 + rr) * 128 + (j & 127)] = 0;
  }

  // Load X (fp32) vectorized: 1600 chunks of 8 consecutive v (32B), bf16
  // convert, one swizzled 16B LDS write each. XOR-swizzle flips only bits
  // >=3 of v, so 8-aligned chunks stay contiguous 16B blocks.
  {
    const float* xb = x + (bq * 4 * T_DIM + t) * GNV;
    for (int idx = tid; idx < 1600; idx += 256) {
      int row = idx >> 4;                  // 0..99  (4 graphs x 25 rows)
      int c8  = (idx & 15) << 3;           // v0 = 0..120 step 8
      int g = (row * 41) >> 10;            // row / 25 (exact for row<100)
      int n = row - g * 25;
      const float4* xp = (const float4*)(xb + g * (T_DIM * GNV) + n * 128 + c8);
      float4 f0 = xp[0], f1 = xp[1];
      uint4 w;
      w.x = pack2bf(f0.x, f0.y); w.y = pack2bf(f0.z, f0.w);
      w.z = pack2bf(f1.x, f1.y); w.w = pack2bf(f1.z, f1.w);
      int r = g * 28 + n;
      *(uint4*)&LB[r * 128 + (c8 ^ ((r & 15) << 3))] = w;
    }
  }

  // W12T B-fragments straight from global (L2-hot), into regs.
  short8 bfr[2][4];
  {
    const unsigned short* Wg = (const unsigned short*)(wsc + WS_W12T);
#pragma unroll
    for (int nt = 0; nt < 2; nt++) {
      const short8* rp = (const short8*)&Wg[(wv * 32 + nt * 16 + l16) * 128];
#pragma unroll
      for (int ks = 0; ks < 4; ks++) bfr[nt][ks] = rp[(ks << 2) | quad];
    }
  }
  __syncthreads();

  // ---- Stage 1: Y = X * W12. Wave wv covers c in [wv*32, +32). 56 MFMA.
  f32x4 acc[7][2];
#pragma unroll
  for (int mt = 0; mt < 7; mt++)
#pragma unroll
    for (int nt = 0; nt < 2; nt++)
#pragma unroll
      for (int r = 0; r < 4; r++) acc[mt][nt][r] = 0.f;

#pragma unroll
  for (int ks = 0; ks < 4; ks++) {
    const int cc = (ks << 2) | quad;
#pragma unroll
    for (int mt = 0; mt < 7; mt++) {
      int arow = mt * 16 + l16;
      short8 afr = *(const short8*)&LB[arow * 128 + ((cc ^ (arow & 15)) << 3)];
#pragma unroll
      for (int nt = 0; nt < 2; nt++)
        acc[mt][nt] = __builtin_amdgcn_mfma_f32_16x16x32_bf16(afr, bfr[nt][ks], acc[mt][nt], 0, 0, 0);
    }
  }
  __syncthreads();  // all X reads done; LB becomes Y_T

  // Write Y -> Y_T (bf16). Each frag: 4 consecutive rows (one graph), col c.
#pragma unroll
  for (int mt = 0; mt < 7; mt++) {
    int row0 = mt * 16 + quad * 4;
    int g = row0 / 28;
    int rl = row0 - g * 28;                // multiple of 4 -> 8B aligned
#pragma unroll
    for (int nt = 0; nt < 2; nt++) {
      int c = wv * 32 + nt * 16 + l16;
      uint2 p;
      p.x = pack2bf(acc[mt][nt][0], acc[mt][nt][1]);
      p.y = pack2bf(acc[mt][nt][2], acc[mt][nt][3]);
      *(uint2*)&LB[g * YGSTR + c * YSTR + rl] = p;
    }
  }
  // zero Y_T pad rows 28..31
  {
    uint2 z; z.x = 0u; z.y = 0u;
    for (int j = tid; j < 512; j += 256) {
      int g = j >> 7, c = j & 127;
      *(uint2*)&LB[g * YGSTR + c * YSTR + 28] = z;
    }
  }
  __syncthreads();

  // ---- Stage 2: H_g = A2 * Y_g. Wave wv <-> graph wv. 16 MFMA.
  const unsigned short* A2p = (const unsigned short*)(wsc + WS_A2P);
  short8 a2f[2];
#pragma unroll
  for (int mt2 = 0; mt2 < 2; mt2++)
    a2f[mt2] = *(const short8*)&A2p[(mt2 * 16 + l16) * 32 + quad * 8];

  const int obase = ((bq * 4 + wv) * T_DIM + t) * GNV;
  float sum = 0.f, ssq = 0.f;
#pragma unroll
  for (int half = 0; half < 2; half++) {
    f32x4 acc2[2][4];
#pragma unroll
    for (int mt2 = 0; mt2 < 2; mt2++)
#pragma unroll
      for (int nt = 0; nt < 4; nt++)
#pragma unroll
        for (int r = 0; r < 4; r++) acc2[mt2][nt][r] = 0.f;

#pragma unroll
    for (int nt = 0; nt < 4; nt++) {
      int c = (half * 4 + nt) * 16 + l16;
      int base = wv * YGSTR + c * YSTR + quad * 8;
      uint2 lo = *(const uint2*)&LB[base];
      uint2 hi = *(const uint2*)&LB[base + 4];
      uint4 w; w.x = lo.x; w.y = lo.y; w.z = hi.x; w.w = hi.y;
      short8 bf = __builtin_bit_cast(short8, w);
#pragma unroll
      for (int mt2 = 0; mt2 < 2; mt2++)
        acc2[mt2][nt] = __builtin_amdgcn_mfma_f32_16x16x32_bf16(a2f[mt2], bf, acc2[mt2][nt], 0, 0, 0);
    }
    // Epilogue for this half: bias + store + stats.
#pragma unroll
    for (int mt2 = 0; mt2 < 2; mt2++) {
#pragma unroll
      for (int nt = 0; nt < 4; nt++) {
        int c = (half * 4 + nt) * 16 + l16;
        float bw = sBW[c], bb = sB2[c];
#pragma unroll
        for (int r = 0; r < 4; r++) {
          int m = mt2 * 16 + quad * 4 + r;
          if (m < N_NODES) {
            float v = acc2[mt2][nt][r] + rs1[m] * bw + bb;
            if (BF16H) {
              unsigned short hv = f2bf(v);
              float vq = bf2f(hv);          // stats on rounded H for self-consistency
              hb[obase + m * 128 + c] = hv;
              sum += vq;
              ssq += vq * vq;
            } else {
              outf[obase + m * 128 + c] = v;
              sum += v;
              ssq += v * v;
            }
          }
        }
      }
    }
  }

#pragma unroll
  for (int off = 32; off > 0; off >>= 1) {
    sum += __shfl_down(sum, off, 64);
    ssq += __shfl_down(ssq, off, 64);
  }
  if (lane == 0) { red[wv] = sum; red[4 + wv] = ssq; }
  __syncthreads();
  if (tid == 0) {
    atomicAdd(&stats[t], red[0] + red[1] + red[2] + red[3]);
    atomicAdd(&stats[128 + t], red[4] + red[5] + red[6] + red[7]);
  }
}

__global__ __launch_bounds__(256, 4) void k_main_h(const float* __restrict__ x,
                                                   const float* __restrict__ b2,
                                                   const float* __restrict__ wsc,
                                                   float* __restrict__ stats,
                                                   unsigned short* __restrict__ hb) {
  k_main_body<1>(x, b2, wsc, stats, hb, nullptr);
}

__global__ __launch_bounds__(256, 4) void k_main_f(const float* __restrict__ x,
                                                   const float* __restrict__ b2,
                                                   const float* __restrict__ wsc,
                                                   float* __restrict__ stats,
                                                   float* __restrict__ outf) {
  k_main_body<0>(x, b2, wsc, stats, nullptr, outf);
}

// ---------------------------------------------------------------------------
// k_norm_h: read bf16 H (L3-hot), write fp32 out ONCE. 8 elems/thread.
__global__ __launch_bounds__(256) void k_norm_h(const unsigned short* __restrict__ hb,
                                                const float* __restrict__ stats,
                                                const float* __restrict__ gamma,
                                                const float* __restrict__ beta,
                                                float* __restrict__ out) {
  const int i8 = (blockIdx.x * 256 + threadIdx.x) * 8;
  const int t = (i8 / GNV) % T_DIM;          // 8 consecutive share t (GNV%8==0)
  const float inv = 1.f / CNT_PER_T;
  float s = stats[t], q = stats[128 + t];
  float mean = s * inv;
  float var = fmaf(q, inv, -mean * mean);
  float rstd = rsqrtf(var + 1e-5f);
  float gm = gamma[t] * rstd;
  float bt = fmaf(-mean, gm, beta[t]);
  uint4 hw = *(const uint4*)(hb + i8);       // 8 bf16
  float4 o0, o1;
  o0.x = fmaxf(fmaf(bf2f((unsigned short)(hw.x & 0xFFFF)), gm, bt), 0.f);
  o0.y = fmaxf(fmaf(bf2f((unsigned short)(hw.x >> 16)),    gm, bt), 0.f);
  o0.z = fmaxf(fmaf(bf2f((unsigned short)(hw.y & 0xFFFF)), gm, bt), 0.f);
  o0.w = fmaxf(fmaf(bf2f((unsigned short)(hw.y >> 16)),    gm, bt), 0.f);
  o1.x = fmaxf(fmaf(bf2f((unsigned short)(hw.z & 0xFFFF)), gm, bt), 0.f);
  o1.y = fmaxf(fmaf(bf2f((unsigned short)(hw.z >> 16)),    gm, bt), 0.f);
  o1.z = fmaxf(fmaf(bf2f((unsigned short)(hw.w & 0xFFFF)), gm, bt), 0.f);
  o1.w = fmaxf(fmaf(bf2f((unsigned short)(hw.w >> 16)),    gm, bt), 0.f);
  *(float4*)(out + i8) = o0;
  *(float4*)(out + i8 + 4) = o1;
}

// ---------------------------------------------------------------------------
// k_norm_f: fallback in-place BatchNorm(T) + affine + ReLU (proven round-1).
#define NORM_STR  1280000   // float4 stride between a thread's 4 accesses
__global__ __launch_bounds__(256) void k_norm_f(float* __restrict__ out,
                                                const float* __restrict__ stats,
                                                const float* __restrict__ gamma,
                                                const float* __restrict__ beta) {
  const int i0 = blockIdx.x * 256 + threadIdx.x;
  const float inv = 1.f / CNT_PER_T;
  float4 h[4];
  float g[4], bb[4];
  int base[4];
#pragma unroll
  for (int k = 0; k < 4; k++) {
    int i4 = i0 + k * NORM_STR;
    base[k] = i4 * 4;
    int t = (base[k] / GNV) % T_DIM;
    float s = stats[t], q = stats[128 + t];
    float mean = s * inv;
    float var = fmaf(q, inv, -mean * mean);
    float rstd = rsqrtf(var + 1e-5f);
    g[k] = gamma[t] * rstd;
    bb[k] = fmaf(-mean, g[k], beta[t]);
    h[k] = *(const float4*)(out + base[k]);
  }
#pragma unroll
  for (int k = 0; k < 4; k++) {
    float4 v = h[k];
    v.x = fmaxf(fmaf(v.x, g[k], bb[k]), 0.f);
    v.y = fmaxf(fmaf(v.y, g[k], bb[k]), 0.f);
    v.z = fmaxf(fmaf(v.z, g[k], bb[k]), 0.f);
    v.w = fmaxf(fmaf(v.w, g[k], bb[k]), 0.f);
    *(float4*)(out + base[k]) = v;
  }
}

// ---------------------------------------------------------------------------
extern "C" void kernel_launch(void* const* d_in, const int* in_sizes, int n_in,
                              void* d_out, int out_size, void* d_ws, size_t ws_size,
                              hipStream_t stream) {
  const float* x     = (const float*)d_in[0];
  const int*   edge  = (const int*)d_in[1];
  const float* W1    = (const float*)d_in[2];
  const float* b1    = (const float*)d_in[3];
  const float* W2    = (const float*)d_in[4];
  const float* b2    = (const float*)d_in[5];
  const float* gamma = (const float*)d_in[6];
  const float* beta  = (const float*)d_in[7];
  float* out = (float*)d_out;
  float* wsf = (float*)d_ws;

  k_pre<<<65, 256, 0, stream>>>(edge, W1, W2, b1, wsf);

  const size_t need = (size_t)WS_HB * 4 + (size_t)TOT_ELEM * 2;
  if (ws_size >= need) {
    unsigned short* hb = (unsigned short*)(wsf + WS_HB);
    k_main_h<<<G_TOTAL / 4, 256, 0, stream>>>(x, b2, wsf, wsf + WS_SUM, hb);
    k_norm_h<<<TOT_ELEM / (256 * 8), 256, 0, stream>>>(hb, wsf + WS_SUM, gamma, beta, out);
  } else {
    k_main_f<<<G_TOTAL / 4, 256, 0, stream>>>(x, b2, wsf, wsf + WS_SUM, out);
    k_norm_f<<<NORM_STR / 256, 256, 0, stream>>>(out, wsf + WS_SUM, gamma, beta);
  }
}